// Round 8
// baseline (348.006 us; speedup 1.0000x reference)
//
#include <hip/hip_runtime.h>
#include <hip/hip_bf16.h>
#include <math.h>

// Problem constants (from reference setup_inputs)
#define B_ROWS 256
#define D_IN   128
#define D_OUT  256
#define M_LEN  4096
#define BETA   50.0f

// out layout (f32): loss[256] | mem_out[4096*256] | md_out[4096*128]
#define OFF_MEM  (B_ROWS)
#define OFF_MD   (B_ROWS + M_LEN * D_OUT)

// ---------------------------------------------------------------------------
// K1 (k_prep): enc = tanh(norm(x)@W1+b1) and loss init to +inf.
// 256 blocks x 256 threads (one block per batch row).  [r5-proven]
// ---------------------------------------------------------------------------
__global__ __launch_bounds__(256) void k_prep(
    const float* __restrict__ x, const float* __restrict__ mean,
    const float* __restrict__ stdv, const float* __restrict__ W1,
    const float* __restrict__ b1, float* __restrict__ enc,
    float* __restrict__ out) {
  __shared__ float sx[D_IN];
  const int b = blockIdx.x, j = threadIdx.x;
  if (j < D_IN) {
    float s = stdv[j];
    sx[j] = (s == 0.0f) ? 0.0f : (x[b * D_IN + j] - mean[j]) / s;
  }
  __syncthreads();
  float acc = b1[j];
#pragma unroll 8
  for (int k = 0; k < D_IN; ++k) acc = fmaf(sx[k], W1[k * D_OUT + j], acc);
  enc[b * D_OUT + j] = tanhf(acc);
  if (b == 0) ((unsigned int*)out)[j] = 0x7F800000u;  // +inf loss init
}

// ---------------------------------------------------------------------------
// K2 (k_dist): loss[b] = min_m sum_d |enc[b,d] - memory[m,d]|
// 256 blocks (32 m-tiles x 8 b-tiles) x 512 threads. Tile 32b x 128m.
// k-split 8: wave w owns k in [32w, 32w+32), 4 sub-chunks of 8 k staged
// into its PRIVATE LDS region (single-buffered, all global loads issued
// up front) -> NO barriers in the main loop.
// Per lane: 8x8 microtile (lane = 4 ro x 16 q) -> per k: 4 ds_read_b128
// per 128 VALU instr => VALU-bound (LDS 384 vs VALU 512 cy/kk/CU).
// LDS k-major; M rows (128 words) stored with chunk-permutation
// p = chunk ^ (chunk>>3): staging b32 stores and b128 reads all <=2-way.
// Cross-wave k-sum via barrier-separated LDS tree (8->4->2->1); fused
// 12.5MB output copy stores issued before the tree (drain under it).
// Tail: per-row min + shfl reduce + atomicMin (distances>=0, init +inf).
// ---------------------------------------------------------------------------
#define TBB 32
#define TMM 128

__global__ __launch_bounds__(512, 2) void k_dist(
    const float* __restrict__ enc, const float* __restrict__ mem,
    const float4* __restrict__ mem4, const float4* __restrict__ md4,
    float* __restrict__ out) {
  __shared__ __align__(16) float sf[10240];  // 40 KB: sE = sf[0..2047], sM = sf[2048..]

  const int t  = threadIdx.x;   // 0..511
  const int w  = t >> 6;        // wave id -> k-range [32w, 32w+32)
  const int l  = t & 63;
  const int ro = l >> 4;        // 0..3  compute: rows 8ro..8ro+7
  const int q  = l & 15;        // 0..15 compute: cols 8q..8q+7
  const int rh = l >> 1;        // 0..31 staging row
  const int h  = l & 1;         // staging k-half (f4)
  const int m0 = blockIdx.x * TMM;
  const int b0 = blockIdx.y * TBB;
  const int bid = blockIdx.y * 32 + blockIdx.x;  // gridDim.x == 32

  // ---- issue ALL global loads up front (in-order completion) ----
  const float* ep = enc + (b0 + rh) * D_OUT + w * 32 + 4 * h;
  const float* mp = mem + (m0 + rh) * D_OUT + w * 32 + 4 * h;
  float4 gE[4], gM[4][4];
#pragma unroll
  for (int c = 0; c < 4; ++c) {
    gE[c] = *(const float4*)(ep + 8 * c);
#pragma unroll
    for (int i = 0; i < 4; ++i)
      gM[c][i] = *(const float4*)(mp + 8 * c + i * 32 * D_OUT);
  }
  // fused output-copy loads (needed only at the very end)
  float4 cm0 = mem4[bid * 1024 + t];
  float4 cm1 = mem4[bid * 1024 + 512 + t];
  float4 cd0 = md4[bid * 512 + t];

  float acc[8][8] = {};
  const int p1 = (2 * q) ^ (q >> 2);  // M chunk position for cols 8q..8q+3

  // ---- main loop: 4 sub-chunks of 8 k, wave-private, no barriers ----
#pragma unroll
  for (int c = 0; c < 4; ++c) {
    {  // E store: 1 f4 -> sE[w][4h+j][rh]   (banks: rh distinct, 2-way free)
      float4 v = gE[c];
      const int base = w * 256 + (4 * h) * 32 + rh;
      sf[base + 0]  = v.x; sf[base + 32] = v.y;
      sf[base + 64] = v.z; sf[base + 96] = v.w;
    }
#pragma unroll
    for (int i = 0; i < 4; ++i) {  // M store: 4 f4, chunk-permuted
      float4 v = gM[c][i];
      const int chunk = (rh >> 2) + 8 * i;    // = row'>>2
      const int p = chunk ^ i;                // chunk ^ (chunk>>3)
      const int base = 2048 + w * 1024 + (4 * h) * 128 + p * 4 + (rh & 3);
      sf[base + 0]   = v.x; sf[base + 128] = v.y;
      sf[base + 256] = v.z; sf[base + 384] = v.w;
    }
    // compute 8 k-layers (full unroll: compile-time LDS offsets)
#pragma unroll
    for (int kl = 0; kl < 8; ++kl) {
      float4 a0 = *(const float4*)&sf[w * 256 + kl * 32 + 8 * ro];
      float4 a1 = *(const float4*)&sf[w * 256 + kl * 32 + 8 * ro + 4];
      float4 bva = *(const float4*)&sf[2048 + w * 1024 + kl * 128 + p1 * 4];
      float4 bvb = *(const float4*)&sf[2048 + w * 1024 + kl * 128 + (p1 ^ 1) * 4];
      float av[8] = {a0.x, a0.y, a0.z, a0.w, a1.x, a1.y, a1.z, a1.w};
      float bw[8] = {bva.x, bva.y, bva.z, bva.w, bvb.x, bvb.y, bvb.z, bvb.w};
#pragma unroll
      for (int i = 0; i < 8; ++i)
#pragma unroll
        for (int j = 0; j < 8; ++j)
          acc[i][j] += fabsf(av[i] - bw[j]);
    }
  }

  // ---- fused copy stores: drain while the combine tree runs ----
  float4* mo = (float4*)(out + OFF_MEM);
  float4* dd = (float4*)(out + OFF_MD);
  mo[bid * 1024 + t] = cm0;
  mo[bid * 1024 + 512 + t] = cm1;
  dd[bid * 512 + t] = cd0;

  // ---- cross-wave k-sum tree: (0<-1)(2<-3)(4<-5)(6<-7), (0<-2)(4<-6), (0<-4)
  // dump layout word = idx*STRIDE + slot*64 + l : contiguous lanes, 2-way banks
  __syncthreads();
  if (w & 1) {  // R1a: odd waves dump acc[0..3][*]
#pragma unroll
    for (int i = 0; i < 4; ++i)
#pragma unroll
      for (int j = 0; j < 8; ++j)
        sf[(i * 8 + j) * 256 + (w >> 1) * 64 + l] = acc[i][j];
  }
  __syncthreads();
  if (!(w & 1)) {
#pragma unroll
    for (int i = 0; i < 4; ++i)
#pragma unroll
      for (int j = 0; j < 8; ++j)
        acc[i][j] += sf[(i * 8 + j) * 256 + (w >> 1) * 64 + l];
  }
  __syncthreads();
  if (w & 1) {  // R1b: odd waves dump acc[4..7][*]
#pragma unroll
    for (int i = 4; i < 8; ++i)
#pragma unroll
      for (int j = 0; j < 8; ++j)
        sf[((i - 4) * 8 + j) * 256 + (w >> 1) * 64 + l] = acc[i][j];
  }
  __syncthreads();
  if (!(w & 1)) {
#pragma unroll
    for (int i = 4; i < 8; ++i)
#pragma unroll
      for (int j = 0; j < 8; ++j)
        acc[i][j] += sf[((i - 4) * 8 + j) * 256 + (w >> 1) * 64 + l];
  }
  __syncthreads();
  if (w == 2 || w == 6) {  // R2 dump (all 64)
#pragma unroll
    for (int i = 0; i < 8; ++i)
#pragma unroll
      for (int j = 0; j < 8; ++j)
        sf[(i * 8 + j) * 128 + (w >> 2) * 64 + l] = acc[i][j];
  }
  __syncthreads();
  if (w == 0 || w == 4) {
#pragma unroll
    for (int i = 0; i < 8; ++i)
#pragma unroll
      for (int j = 0; j < 8; ++j)
        acc[i][j] += sf[(i * 8 + j) * 128 + (w >> 2) * 64 + l];
  }
  __syncthreads();
  if (w == 4) {  // R3 dump
#pragma unroll
    for (int i = 0; i < 8; ++i)
#pragma unroll
      for (int j = 0; j < 8; ++j)
        sf[(i * 8 + j) * 64 + l] = acc[i][j];
  }
  __syncthreads();
  if (w == 0) {  // final sums in wave 0; row-min + cross-q shfl + atomicMin
#pragma unroll
    for (int i = 0; i < 8; ++i) {
      float rm = 3.4e38f;
#pragma unroll
      for (int j = 0; j < 8; ++j)
        rm = fminf(rm, acc[i][j] + sf[(i * 8 + j) * 64 + l]);
      rm = fminf(rm, __shfl_xor(rm, 1));
      rm = fminf(rm, __shfl_xor(rm, 2));
      rm = fminf(rm, __shfl_xor(rm, 4));
      rm = fminf(rm, __shfl_xor(rm, 8));
      if (q == 0)
        atomicMin((unsigned int*)out + (b0 + 8 * ro + i), __float_as_uint(rm));
    }
  }
}

// ---------------------------------------------------------------------------
// K3 (k_scatter): sequential circular-buffer update collapsed to
// ballot/prefix + scatter (count starts at M_LEN so positions wrap from 0).
// ---------------------------------------------------------------------------
__global__ __launch_bounds__(256) void k_scatter(float* __restrict__ out,
                                                 const float* __restrict__ enc,
                                                 const float* __restrict__ x) {
  __shared__ int wcount[4];
  int t = threadIdx.x;
  float l = out[t];  // final loss
  bool cond = isfinite(l) && (l <= BETA);
  unsigned long long m = __ballot(cond);
  int lane = t & 63;
  int wv   = t >> 6;
  int pre_in_wave = __popcll(m & ((1ull << lane) - 1ull));
  if (lane == 0) wcount[wv] = (int)__popcll(m);
  __syncthreads();
  int base = 0;
  for (int w = 0; w < wv; ++w) base += wcount[w];
  if (cond) {
    int pos = base + pre_in_wave;  // (M_LEN + prefix) % M_LEN
    float* mrow = out + OFF_MEM + pos * D_OUT;
    const float* erow = enc + t * D_OUT;
    for (int d = 0; d < D_OUT; ++d) mrow[d] = erow[d];
    float* drow = out + OFF_MD + pos * D_IN;
    const float* xrow = x + t * D_IN;
    for (int d = 0; d < D_IN; ++d) drow[d] = xrow[d];
  }
}

// ---------------------------------------------------------------------------
extern "C" void kernel_launch(void* const* d_in, const int* in_sizes, int n_in,
                              void* d_out, int out_size, void* d_ws, size_t ws_size,
                              hipStream_t stream) {
  const float* x      = (const float*)d_in[0];
  const float* mean   = (const float*)d_in[1];
  const float* stdv   = (const float*)d_in[2];
  const float* W1     = (const float*)d_in[3];
  const float* b1     = (const float*)d_in[4];
  const float* memory = (const float*)d_in[5];
  const float* memdat = (const float*)d_in[6];
  float* out = (float*)d_out;
  float* enc = (float*)d_ws;  // 256*256*4 = 256KB scratch

  k_prep<<<dim3(B_ROWS), dim3(256), 0, stream>>>(x, mean, stdv, W1, b1, enc, out);

  k_dist<<<dim3(M_LEN / TMM, B_ROWS / TBB), dim3(512), 0, stream>>>(
      enc, memory, (const float4*)memory, (const float4*)memdat, out);

  k_scatter<<<dim3(1), dim3(256), 0, stream>>>(out, enc, x);
}

// Round 9
// 315.179 us; speedup vs baseline: 1.1042x; 1.1042x over previous
//
#include <hip/hip_runtime.h>
#include <hip/hip_bf16.h>
#include <math.h>

// Problem constants (from reference setup_inputs)
#define B_ROWS 256
#define D_IN   128
#define D_OUT  256
#define M_LEN  4096
#define BETA   50.0f

// out layout (f32): loss[256] | mem_out[4096*256] | md_out[4096*128]
#define OFF_MEM  (B_ROWS)
#define OFF_MD   (B_ROWS + M_LEN * D_OUT)

// ---------------------------------------------------------------------------
// K1 (k_prep): enc = tanh(norm(x)@W1+b1) and loss init to +inf.  [r5-proven]
// ---------------------------------------------------------------------------
__global__ __launch_bounds__(256) void k_prep(
    const float* __restrict__ x, const float* __restrict__ mean,
    const float* __restrict__ stdv, const float* __restrict__ W1,
    const float* __restrict__ b1, float* __restrict__ enc,
    float* __restrict__ out) {
  __shared__ float sx[D_IN];
  const int b = blockIdx.x, j = threadIdx.x;
  if (j < D_IN) {
    float s = stdv[j];
    sx[j] = (s == 0.0f) ? 0.0f : (x[b * D_IN + j] - mean[j]) / s;
  }
  __syncthreads();
  float acc = b1[j];
#pragma unroll 8
  for (int k = 0; k < D_IN; ++k) acc = fmaf(sx[k], W1[k * D_OUT + j], acc);
  enc[b * D_OUT + j] = tanhf(acc);
  if (b == 0) ((unsigned int*)out)[j] = 0x7F800000u;  // +inf loss init
}

// ---------------------------------------------------------------------------
// K2 (k_dist): loss[b] = min_m sum_d |enc[b,d] - memory[m,d]|
// 256 blocks (32 m-tiles x 8 b-tiles) x 512 threads. Tile 32b x 128m.
// k-split 8: wave w owns k in [32w,32w+32) as 4 JIT-staged chunks of 8 k
// in its PRIVATE 1280-float LDS region -> no main-loop barriers.
// 8x8 microtile/lane: 4 ds_read_b128 per 128 VALU instr -> VALU-bound.
// M columns stored permuted pos(c)=((c>>3)<<2)+(c&3)+(((c>>2)&1)<<6):
// reads land at 4q and 64+4q -> 8 bank-groups, 2-way (free).
// Register discipline: one 20-VGPR prefetch set in flight; launch_bounds
// without min-wave clause (VGPR cap 256) -> no spill (r8 lesson).
// Fused FULL output copy (loads early, stores before combine tree).
// Cross-wave k-sum via r8's validated barrier tree; atomicMin tail.
// ---------------------------------------------------------------------------
#define TBB 32
#define TMM 128

__global__ __launch_bounds__(512) void k_dist(
    const float* __restrict__ enc, const float* __restrict__ mem,
    const float4* __restrict__ mem4, const float4* __restrict__ md4,
    float* __restrict__ out) {
  __shared__ __align__(16) float sf[10240];  // 40KB: 8 waves x (E 256 + M 1024)

  const int t  = threadIdx.x;   // 0..511
  const int w  = t >> 6;        // wave id -> k-range [32w, 32w+32)
  const int l  = t & 63;
  const int ro = l >> 4;        // 0..3  compute: rows 8ro..8ro+7
  const int q  = l & 15;        // 0..15 compute: cols 8q..8q+7
  const int rh = l >> 1;        // 0..31 staging row
  const int h  = l & 1;         // staging k-half (f4)
  const int m0 = blockIdx.x * TMM;
  const int b0 = blockIdx.y * TBB;
  const int bid = blockIdx.y * 32 + blockIdx.x;  // gridDim.x == 32

  const float* ep = enc + (b0 + rh) * D_OUT + w * 32 + 4 * h;
  const float* mp = mem + (m0 + rh) * D_OUT + w * 32 + 4 * h;

  const int eb = w * 1280;        // E region: [kk][32]
  const int mb = w * 1280 + 256;  // M region: [kk][128 permuted]
  // M store position for col c=rh+32i: pos = mpos + 16*i
  const int mpos = ((rh >> 3) << 2) + (rh & 3) + (((rh >> 2) & 1) << 6);

  float4 eA, mA[4], eB, mB[4];
  float acc[8][8] = {};

#define LOADC(e_, m_, c_)                                              \
  do {                                                                 \
    e_ = *(const float4*)(ep + 8 * (c_));                              \
    m_[0] = *(const float4*)(mp + 8 * (c_));                           \
    m_[1] = *(const float4*)(mp + 8 * (c_) + 32 * D_OUT);              \
    m_[2] = *(const float4*)(mp + 8 * (c_) + 64 * D_OUT);              \
    m_[3] = *(const float4*)(mp + 8 * (c_) + 96 * D_OUT);              \
  } while (0)

#define STOREC(e_, m_)                                                 \
  do {                                                                 \
    const int beb = eb + 4 * h * 32 + rh;                              \
    sf[beb] = e_.x; sf[beb + 32] = e_.y;                               \
    sf[beb + 64] = e_.z; sf[beb + 96] = e_.w;                          \
    _Pragma("unroll")                                                  \
    for (int i = 0; i < 4; ++i) {                                      \
      const int bmb = mb + 4 * h * 128 + mpos + 16 * i;                \
      sf[bmb] = m_[i].x;       sf[bmb + 128] = m_[i].y;                \
      sf[bmb + 256] = m_[i].z; sf[bmb + 384] = m_[i].w;                \
    }                                                                  \
  } while (0)

#define COMPUTEC()                                                     \
  do {                                                                 \
    _Pragma("unroll")                                                  \
    for (int kl = 0; kl < 8; ++kl) {                                   \
      float4 a0 = *(const float4*)&sf[eb + kl * 32 + 8 * ro];          \
      float4 a1 = *(const float4*)&sf[eb + kl * 32 + 8 * ro + 4];      \
      float4 v0 = *(const float4*)&sf[mb + kl * 128 + 4 * q];          \
      float4 v1 = *(const float4*)&sf[mb + kl * 128 + 64 + 4 * q];     \
      float av[8] = {a0.x, a0.y, a0.z, a0.w, a1.x, a1.y, a1.z, a1.w};  \
      float bw[8] = {v0.x, v0.y, v0.z, v0.w, v1.x, v1.y, v1.z, v1.w};  \
      _Pragma("unroll")                                                \
      for (int i = 0; i < 8; ++i)                                      \
        _Pragma("unroll")                                              \
        for (int j = 0; j < 8; ++j)                                    \
          acc[i][j] += fabsf(av[i] - bw[j]);                           \
    }                                                                  \
  } while (0)

  // fused output-copy loads (consumed only at the end)
  float4 cm0 = mem4[bid * 1024 + t];
  float4 cm1 = mem4[bid * 1024 + 512 + t];
  float4 cd0 = md4[bid * 512 + t];

  // pipeline: L0 S0 L1 C0 S1 L2 C1 S2 L3 C2 S3 C3  (wave-private, in-order LDS)
  LOADC(eA, mA, 0);
  STOREC(eA, mA);
  LOADC(eB, mB, 1);
  COMPUTEC();
  STOREC(eB, mB);
  LOADC(eA, mA, 2);
  COMPUTEC();
  STOREC(eA, mA);
  LOADC(eB, mB, 3);
  COMPUTEC();
  STOREC(eB, mB);
  COMPUTEC();

  // ---- fused copy stores: drain while the combine tree runs ----
  float4* mo = (float4*)(out + OFF_MEM);
  float4* dd = (float4*)(out + OFF_MD);
  mo[bid * 1024 + t] = cm0;
  mo[bid * 1024 + 512 + t] = cm1;
  dd[bid * 512 + t] = cd0;

  // ---- cross-wave k-sum tree (r8-validated): pairs, then quads, then final
  __syncthreads();
  if (w & 1) {  // R1a: odd waves dump acc[0..3][*]
#pragma unroll
    for (int i = 0; i < 4; ++i)
#pragma unroll
      for (int j = 0; j < 8; ++j)
        sf[(i * 8 + j) * 256 + (w >> 1) * 64 + l] = acc[i][j];
  }
  __syncthreads();
  if (!(w & 1)) {
#pragma unroll
    for (int i = 0; i < 4; ++i)
#pragma unroll
      for (int j = 0; j < 8; ++j)
        acc[i][j] += sf[(i * 8 + j) * 256 + (w >> 1) * 64 + l];
  }
  __syncthreads();
  if (w & 1) {  // R1b: odd waves dump acc[4..7][*]
#pragma unroll
    for (int i = 4; i < 8; ++i)
#pragma unroll
      for (int j = 0; j < 8; ++j)
        sf[((i - 4) * 8 + j) * 256 + (w >> 1) * 64 + l] = acc[i][j];
  }
  __syncthreads();
  if (!(w & 1)) {
#pragma unroll
    for (int i = 4; i < 8; ++i)
#pragma unroll
      for (int j = 0; j < 8; ++j)
        acc[i][j] += sf[((i - 4) * 8 + j) * 256 + (w >> 1) * 64 + l];
  }
  __syncthreads();
  if (w == 2 || w == 6) {  // R2 dump
#pragma unroll
    for (int i = 0; i < 8; ++i)
#pragma unroll
      for (int j = 0; j < 8; ++j)
        sf[(i * 8 + j) * 128 + (w >> 2) * 64 + l] = acc[i][j];
  }
  __syncthreads();
  if (w == 0 || w == 4) {
#pragma unroll
    for (int i = 0; i < 8; ++i)
#pragma unroll
      for (int j = 0; j < 8; ++j)
        acc[i][j] += sf[(i * 8 + j) * 128 + (w >> 2) * 64 + l];
  }
  __syncthreads();
  if (w == 4) {  // R3 dump
#pragma unroll
    for (int i = 0; i < 8; ++i)
#pragma unroll
      for (int j = 0; j < 8; ++j)
        sf[(i * 8 + j) * 64 + l] = acc[i][j];
  }
  __syncthreads();
  if (w == 0) {  // final sums; row-min + cross-q shfl + atomicMin
#pragma unroll
    for (int i = 0; i < 8; ++i) {
      float rm = 3.4e38f;
#pragma unroll
      for (int j = 0; j < 8; ++j)
        rm = fminf(rm, acc[i][j] + sf[(i * 8 + j) * 64 + l]);
      rm = fminf(rm, __shfl_xor(rm, 1));
      rm = fminf(rm, __shfl_xor(rm, 2));
      rm = fminf(rm, __shfl_xor(rm, 4));
      rm = fminf(rm, __shfl_xor(rm, 8));
      if (q == 0)  // distances >= 0, init +inf -> uint-bit atomicMin valid
        atomicMin((unsigned int*)out + (b0 + 8 * ro + i), __float_as_uint(rm));
    }
  }
}

// ---------------------------------------------------------------------------
// K3 (k_scatter): sequential circular-buffer update collapsed to
// ballot/prefix + scatter (count starts at M_LEN so positions wrap from 0).
// ---------------------------------------------------------------------------
__global__ __launch_bounds__(256) void k_scatter(float* __restrict__ out,
                                                 const float* __restrict__ enc,
                                                 const float* __restrict__ x) {
  __shared__ int wcount[4];
  int t = threadIdx.x;
  float l = out[t];  // final loss
  bool cond = isfinite(l) && (l <= BETA);
  unsigned long long m = __ballot(cond);
  int lane = t & 63;
  int wv   = t >> 6;
  int pre_in_wave = __popcll(m & ((1ull << lane) - 1ull));
  if (lane == 0) wcount[wv] = (int)__popcll(m);
  __syncthreads();
  int base = 0;
  for (int w = 0; w < wv; ++w) base += wcount[w];
  if (cond) {
    int pos = base + pre_in_wave;  // (M_LEN + prefix) % M_LEN
    float* mrow = out + OFF_MEM + pos * D_OUT;
    const float* erow = enc + t * D_OUT;
    for (int d = 0; d < D_OUT; ++d) mrow[d] = erow[d];
    float* drow = out + OFF_MD + pos * D_IN;
    const float* xrow = x + t * D_IN;
    for (int d = 0; d < D_IN; ++d) drow[d] = xrow[d];
  }
}

// ---------------------------------------------------------------------------
extern "C" void kernel_launch(void* const* d_in, const int* in_sizes, int n_in,
                              void* d_out, int out_size, void* d_ws, size_t ws_size,
                              hipStream_t stream) {
  const float* x      = (const float*)d_in[0];
  const float* mean   = (const float*)d_in[1];
  const float* stdv   = (const float*)d_in[2];
  const float* W1     = (const float*)d_in[3];
  const float* b1     = (const float*)d_in[4];
  const float* memory = (const float*)d_in[5];
  const float* memdat = (const float*)d_in[6];
  float* out = (float*)d_out;
  float* enc = (float*)d_ws;  // 256*256*4 = 256KB scratch

  k_prep<<<dim3(B_ROWS), dim3(256), 0, stream>>>(x, mean, stdv, W1, b1, enc, out);

  k_dist<<<dim3(M_LEN / TMM, B_ROWS / TBB), dim3(512), 0, stream>>>(
      enc, memory, (const float4*)memory, (const float4*)memdat, out);

  k_scatter<<<dim3(1), dim3(256), 0, stream>>>(out, enc, x);
}

// Round 10
// 39.932 us; speedup vs baseline: 8.7149x; 7.8928x over previous
//
#include <hip/hip_runtime.h>
#include <hip/hip_bf16.h>
#include <math.h>

// Problem constants (from reference setup_inputs)
#define B_ROWS 256
#define D_IN   128
#define D_OUT  256
#define M_LEN  4096
#define BETA   50.0f

// out layout (f32): loss[256] | mem_out[4096*256] | md_out[4096*128]
#define OFF_MEM  (B_ROWS)
#define OFF_MD   (B_ROWS + M_LEN * D_OUT)

// ws layout (float idx): enc[65536] | done-flag int
#define ENC_F   0
#define FLAG_F  65536

// ---------------------------------------------------------------------------
// K1 (k_prep): enc = tanh(norm(x)@W1+b1), loss init to +inf, zero done-flag.
// 256 blocks x 256 threads (one block per batch row).  [r5-proven]
// ---------------------------------------------------------------------------
__global__ __launch_bounds__(256) void k_prep(
    const float* __restrict__ x, const float* __restrict__ mean,
    const float* __restrict__ stdv, const float* __restrict__ W1,
    const float* __restrict__ b1, float* __restrict__ ws,
    float* __restrict__ out) {
  __shared__ float sx[D_IN];
  float* enc = ws + ENC_F;
  const int b = blockIdx.x, j = threadIdx.x;
  if (j < D_IN) {
    float s = stdv[j];
    sx[j] = (s == 0.0f) ? 0.0f : (x[b * D_IN + j] - mean[j]) / s;
  }
  __syncthreads();
  float acc = b1[j];
#pragma unroll 8
  for (int k = 0; k < D_IN; ++k) acc = fmaf(sx[k], W1[k * D_OUT + j], acc);
  enc[b * D_OUT + j] = tanhf(acc);
  if (b == 0) ((unsigned int*)out)[j] = 0x7F800000u;  // +inf loss init
  if (b == 0 && j == 0)
    __hip_atomic_store((int*)(ws + FLAG_F), 0, __ATOMIC_RELAXED,
                       __HIP_MEMORY_SCOPE_AGENT);
}

// ---------------------------------------------------------------------------
// K2 (k_dist): loss[b] = min_m sum_d |enc[b,d] - memory[m,d]|
// [byte-identical to the r5 27.3us champion main body]
// 512 blocks (64 m-tiles x 8 b-tiles) x 256 threads. Tile 32b x 64m.
// k-split 4: wave w owns k in [64w, 64w+64), staged as 2 chunks of 32 into
// its PRIVATE LDS region -> NO barriers in the main loop.
// 4x8 microtile/lane; LDS k-major, XOR swizzle row^=4*(k>>2) -> 2-way banks.
// Fused FULL memory->out / mem_data->out copy (loads early, stores late).
// NEW vs r5: after the copy stores, a release done-counter; the last block
// runs the ballot/prefix circular-buffer scatter inline (replaces k_scatter).
// No __threadfence, no unroll changes (r7 lesson: isolate one variable).
// ---------------------------------------------------------------------------
#define TB 32
#define TM 64

__global__ __launch_bounds__(256) void k_dist(
    const float* __restrict__ x, const float* __restrict__ mem,
    const float4* __restrict__ mem4, const float4* __restrict__ md4,
    float* __restrict__ ws, float* __restrict__ out) {
  __shared__ __align__(16) float sE[4][32][TB];  // [wave][kk][row^swz] 16KB
  __shared__ __align__(16) float sM[4][32][TM];  // [wave][kk][row^swz] 32KB
  __shared__ int wcount[4];
  __shared__ int slast;

  float* enc = ws + ENC_F;
  int*   don = (int*)(ws + FLAG_F);

  const int t  = threadIdx.x;
  const int w  = t >> 6;     // wave id -> k-quarter
  const int l  = t & 63;
  const int ro = l >> 3;     // 0..7 staging row-offset; compute tr
  const int q  = l & 7;      // 0..7 staging f4-k index; compute tc
  const int m0 = blockIdx.x * TM;
  const int b0 = blockIdx.y * TB;
  const int bid = blockIdx.y * 64 + blockIdx.x;  // gridDim.x == 64

  const float* encp = enc + (b0 + ro) * D_OUT + w * 64 + q * 4;
  const float* memp = mem + (m0 + ro) * D_OUT + w * 64 + q * 4;

  float4 rE[4], rM[8], rE2[4], rM2[8];
  float acc[4][8] = {};

  auto store_lds = [&](const float4* e, const float4* m) {
#pragma unroll
    for (int i = 0; i < 4; ++i) {
      const int row = (i * 8 + ro) ^ (q * 4);
      sE[w][q * 4 + 0][row] = e[i].x;
      sE[w][q * 4 + 1][row] = e[i].y;
      sE[w][q * 4 + 2][row] = e[i].z;
      sE[w][q * 4 + 3][row] = e[i].w;
    }
#pragma unroll
    for (int i = 0; i < 8; ++i) {
      const int row = (i * 8 + ro) ^ (q * 4);
      sM[w][q * 4 + 0][row] = m[i].x;
      sM[w][q * 4 + 1][row] = m[i].y;
      sM[w][q * 4 + 2][row] = m[i].z;
      sM[w][q * 4 + 3][row] = m[i].w;
    }
  };

  auto compute = [&]() {
#pragma unroll
    for (int kk = 0; kk < 32; ++kk) {
      const int sw = (kk >> 2) * 4;
      float4 a   = *(const float4*)&sE[w][kk][(ro * 4) ^ sw];
      float4 bv1 = *(const float4*)&sM[w][kk][(q * 8) ^ sw];
      float4 bv2 = *(const float4*)&sM[w][kk][(q * 8 + 4) ^ sw];
      float av[4] = {a.x, a.y, a.z, a.w};
      float bw[8] = {bv1.x, bv1.y, bv1.z, bv1.w, bv2.x, bv2.y, bv2.z, bv2.w};
#pragma unroll
      for (int i = 0; i < 4; ++i)
#pragma unroll
        for (int j = 0; j < 8; ++j)
          acc[i][j] += fabsf(av[i] - bw[j]);
    }
  };

  // chunk 0 loads (coalesced: 8 consecutive lanes = 128B run)
#pragma unroll
  for (int i = 0; i < 4; ++i) rE[i] = *(const float4*)(encp + i * 8 * D_OUT);
#pragma unroll
  for (int i = 0; i < 8; ++i) rM[i] = *(const float4*)(memp + i * 8 * D_OUT);
  store_lds(rE, rM);

  // prefetch chunk 1 (+32 k)
#pragma unroll
  for (int i = 0; i < 4; ++i) rE2[i] = *(const float4*)(encp + 32 + i * 8 * D_OUT);
#pragma unroll
  for (int i = 0; i < 8; ++i) rM2[i] = *(const float4*)(memp + 32 + i * 8 * D_OUT);

  // fused output-copy loads (complete by the tail stores)
  float4 cm0 = mem4[bid * 512 + t];
  float4 cm1 = mem4[bid * 512 + 256 + t];
  float4 cd0 = md4[bid * 256 + t];

  compute();               // chunk 0
  store_lds(rE2, rM2);     // same-wave WAR on LDS: in-order per wave
  compute();               // chunk 1

  // ---- combine across the 4 k-quarter waves ----
  float* sf = &sM[0][0][0];
#pragma unroll
  for (int i = 0; i < 4; ++i)
#pragma unroll
    for (int j = 0; j < 8; ++j) {
      const int p = i * 8 + j;
      sf[w * 2048 + l * 32 + (p ^ (l & 31))] = acc[i][j];
    }
  __syncthreads();

  {
    const int r = t >> 3, cg = t & 7;
    const int lv = (r >> 2) * 8 + cg;
    float dmin = 3.4e38f;
#pragma unroll
    for (int j = 0; j < 8; ++j) {
      const int p = (r & 3) * 8 + j;
      float s = sf[0 * 2048 + lv * 32 + (p ^ (lv & 31))];
      s += sf[1 * 2048 + lv * 32 + (p ^ (lv & 31))];
      s += sf[2 * 2048 + lv * 32 + (p ^ (lv & 31))];
      s += sf[3 * 2048 + lv * 32 + (p ^ (lv & 31))];
      dmin = fminf(dmin, s);
    }
    dmin = fminf(dmin, __shfl_xor(dmin, 1));
    dmin = fminf(dmin, __shfl_xor(dmin, 2));
    dmin = fminf(dmin, __shfl_xor(dmin, 4));
    if (cg == 0)  // distances >= 0, init +inf -> uint-bit atomicMin valid
      atomicMin((unsigned int*)out + (b0 + r), __float_as_uint(dmin));
  }

  // ---- complete fused copy ----
  float4* mo = (float4*)(out + OFF_MEM);
  float4* dd = (float4*)(out + OFF_MD);
  mo[bid * 512 + t] = cm0;
  mo[bid * 512 + 256 + t] = cm1;
  dd[bid * 256 + t] = cd0;

  // ---- done-counter (release orders the stores above); last block scatters
  __syncthreads();
  if (t == 0) {
    int old = __hip_atomic_fetch_add(don, 1, __ATOMIC_ACQ_REL,
                                     __HIP_MEMORY_SCOPE_AGENT);
    slast = (old == 511) ? 1 : 0;
  }
  __syncthreads();
  if (!slast) return;

  {
    unsigned int lu = __hip_atomic_load((unsigned int*)out + t,
                                        __ATOMIC_RELAXED,
                                        __HIP_MEMORY_SCOPE_AGENT);
    float mn = __uint_as_float(lu);
    bool cond = isfinite(mn) && (mn <= BETA);
    unsigned long long bm = __ballot(cond);
    int lane = t & 63, wv = t >> 6;
    int pre = __popcll(bm & ((1ull << lane) - 1ull));
    if (lane == 0) wcount[wv] = (int)__popcll(bm);
    __syncthreads();
    int base = 0;
    for (int wj = 0; wj < wv; ++wj) base += wcount[wj];
    if (cond) {
      int pos = base + pre;  // (M_LEN + prefix) % M_LEN
      float* mrow = out + OFF_MEM + pos * D_OUT;
      const float* erow = enc + t * D_OUT;
      for (int d = 0; d < D_OUT; ++d) mrow[d] = erow[d];
      float* drow = out + OFF_MD + pos * D_IN;
      const float* xrow = x + t * D_IN;
      for (int d = 0; d < D_IN; ++d) drow[d] = xrow[d];
    }
  }
}

// ---------------------------------------------------------------------------
extern "C" void kernel_launch(void* const* d_in, const int* in_sizes, int n_in,
                              void* d_out, int out_size, void* d_ws, size_t ws_size,
                              hipStream_t stream) {
  const float* x      = (const float*)d_in[0];
  const float* mean   = (const float*)d_in[1];
  const float* stdv   = (const float*)d_in[2];
  const float* W1     = (const float*)d_in[3];
  const float* b1     = (const float*)d_in[4];
  const float* memory = (const float*)d_in[5];
  const float* memdat = (const float*)d_in[6];
  float* out = (float*)d_out;
  float* ws  = (float*)d_ws;

  k_prep<<<dim3(B_ROWS), dim3(256), 0, stream>>>(x, mean, stdv, W1, b1, ws, out);

  k_dist<<<dim3(M_LEN / TM, B_ROWS / TB), dim3(256), 0, stream>>>(
      x, memory, (const float4*)memory, (const float4*)memdat, ws, out);
}

// Round 11
// 26.351 us; speedup vs baseline: 13.2063x; 1.5154x over previous
//
#include <hip/hip_runtime.h>
#include <hip/hip_bf16.h>
#include <math.h>

// Problem constants (from reference setup_inputs)
#define B_ROWS 256
#define D_IN   128
#define D_OUT  256
#define M_LEN  4096
#define BETA   50.0f

// out layout (f32): loss[256] | mem_out[4096*256] | md_out[4096*128]
#define OFF_MEM  (B_ROWS)
#define OFF_MD   (B_ROWS + M_LEN * D_OUT)

// ---------------------------------------------------------------------------
// K1 (k_prep): enc = tanh(norm(x)@W1+b1) and loss init to +inf.
// 256 blocks x 256 threads (one block per batch row).  [r5-proven]
// ---------------------------------------------------------------------------
__global__ __launch_bounds__(256) void k_prep(
    const float* __restrict__ x, const float* __restrict__ mean,
    const float* __restrict__ stdv, const float* __restrict__ W1,
    const float* __restrict__ b1, float* __restrict__ enc,
    float* __restrict__ out) {
  __shared__ float sx[D_IN];
  const int b = blockIdx.x, j = threadIdx.x;
  if (j < D_IN) {
    float s = stdv[j];
    sx[j] = (s == 0.0f) ? 0.0f : (x[b * D_IN + j] - mean[j]) / s;
  }
  __syncthreads();
  float acc = b1[j];
#pragma unroll 8
  for (int k = 0; k < D_IN; ++k) acc = fmaf(sx[k], W1[k * D_OUT + j], acc);
  enc[b * D_OUT + j] = tanhf(acc);
  if (b == 0) ((unsigned int*)out)[j] = 0x7F800000u;  // +inf loss init
}

// ---------------------------------------------------------------------------
// K2 (k_dist): loss[b] = min_m sum_d |enc[b,d] - memory[m,d]|
// [r5 champion body; ONE change: compute() uses an explicit 4-deep rotating
//  register prefetch (compile-time indices) so each kk's 3 ds_read_b128 are
//  issued ~512 VALU-cycles before use -> LDS latency hidden. VGPR budget is
//  free: grid 512 x 256thr caps occupancy at 2 blocks/CU regardless.]
// 512 blocks (64 m-tiles x 8 b-tiles) x 256 threads. Tile 32b x 64m.
// k-split 4: wave w owns k in [64w, 64w+64), 2 chunks of 32 kk, PRIVATE LDS
// region per wave -> NO barriers in the main loop. 4x8 microtile/lane.
// LDS k-major, XOR swizzle row^=4*(k>>2): staging b32 stores and b128 reads
// verified <=2-way (free). Staging loads 8-lane-contiguous (128B runs).
// Fused FULL memory->out / mem_data->out copy (loads early, stores late).
// ---------------------------------------------------------------------------
#define TB 32
#define TM 64

__global__ __launch_bounds__(256) void k_dist(
    const float* __restrict__ enc, const float* __restrict__ mem,
    const float4* __restrict__ mem4, const float4* __restrict__ md4,
    float* __restrict__ out) {
  __shared__ __align__(16) float sE[4][32][TB];  // [wave][kk][row^swz] 16KB
  __shared__ __align__(16) float sM[4][32][TM];  // [wave][kk][row^swz] 32KB

  const int t  = threadIdx.x;
  const int w  = t >> 6;     // wave id -> k-quarter
  const int l  = t & 63;
  const int ro = l >> 3;     // 0..7 staging row-offset; compute tr
  const int q  = l & 7;      // 0..7 staging f4-k index; compute tc
  const int m0 = blockIdx.x * TM;
  const int b0 = blockIdx.y * TB;
  const int bid = blockIdx.y * 64 + blockIdx.x;  // gridDim.x == 64

  const float* encp = enc + (b0 + ro) * D_OUT + w * 64 + q * 4;
  const float* memp = mem + (m0 + ro) * D_OUT + w * 64 + q * 4;

  float4 rE[4], rM[8], rE2[4], rM2[8];
  float acc[4][8] = {};

  auto store_lds = [&](const float4* e, const float4* m) {
#pragma unroll
    for (int i = 0; i < 4; ++i) {
      const int row = (i * 8 + ro) ^ (q * 4);
      sE[w][q * 4 + 0][row] = e[i].x;
      sE[w][q * 4 + 1][row] = e[i].y;
      sE[w][q * 4 + 2][row] = e[i].z;
      sE[w][q * 4 + 3][row] = e[i].w;
    }
#pragma unroll
    for (int i = 0; i < 8; ++i) {
      const int row = (i * 8 + ro) ^ (q * 4);
      sM[w][q * 4 + 0][row] = m[i].x;
      sM[w][q * 4 + 1][row] = m[i].y;
      sM[w][q * 4 + 2][row] = m[i].z;
      sM[w][q * 4 + 3][row] = m[i].w;
    }
  };

  auto rdE = [&](int kk) -> float4 {
    const int sw = (kk >> 2) * 4;
    return *(const float4*)&sE[w][kk][(ro * 4) ^ sw];
  };
  auto rdM1 = [&](int kk) -> float4 {
    const int sw = (kk >> 2) * 4;
    return *(const float4*)&sM[w][kk][(q * 8) ^ sw];
  };
  auto rdM2 = [&](int kk) -> float4 {
    const int sw = (kk >> 2) * 4;
    return *(const float4*)&sM[w][kk][(q * 8 + 4) ^ sw];
  };

  auto compute = [&]() {
    float4 bE[4], bM1[4], bM2[4];  // rotating prefetch regs (static indices)
#pragma unroll
    for (int p = 0; p < 4; ++p) {
      bE[p] = rdE(p); bM1[p] = rdM1(p); bM2[p] = rdM2(p);
    }
#pragma unroll
    for (int kk = 0; kk < 32; ++kk) {
      const int s = kk & 3;
      float4 a  = bE[s];
      float4 v1 = bM1[s];
      float4 v2 = bM2[s];
      if (kk + 4 < 32) {  // issue kk+4's reads before kk's 64 VALU ops
        bE[s] = rdE(kk + 4); bM1[s] = rdM1(kk + 4); bM2[s] = rdM2(kk + 4);
      }
      float av[4] = {a.x, a.y, a.z, a.w};
      float bw[8] = {v1.x, v1.y, v1.z, v1.w, v2.x, v2.y, v2.z, v2.w};
#pragma unroll
      for (int i = 0; i < 4; ++i)
#pragma unroll
        for (int j = 0; j < 8; ++j)
          acc[i][j] += fabsf(av[i] - bw[j]);
    }
  };

  // chunk 0 loads (coalesced: 8 consecutive lanes = 128B run)
#pragma unroll
  for (int i = 0; i < 4; ++i) rE[i] = *(const float4*)(encp + i * 8 * D_OUT);
#pragma unroll
  for (int i = 0; i < 8; ++i) rM[i] = *(const float4*)(memp + i * 8 * D_OUT);
  store_lds(rE, rM);

  // prefetch chunk 1 (+32 k)
#pragma unroll
  for (int i = 0; i < 4; ++i) rE2[i] = *(const float4*)(encp + 32 + i * 8 * D_OUT);
#pragma unroll
  for (int i = 0; i < 8; ++i) rM2[i] = *(const float4*)(memp + 32 + i * 8 * D_OUT);

  // fused output-copy loads (complete by the tail stores)
  float4 cm0 = mem4[bid * 512 + t];
  float4 cm1 = mem4[bid * 512 + 256 + t];
  float4 cd0 = md4[bid * 256 + t];

  compute();               // chunk 0
  store_lds(rE2, rM2);     // same-wave WAR on LDS: in-order per wave
  compute();               // chunk 1

  // ---- combine across the 4 k-quarter waves ----
  float* sf = &sM[0][0][0];
#pragma unroll
  for (int i = 0; i < 4; ++i)
#pragma unroll
    for (int j = 0; j < 8; ++j) {
      const int p = i * 8 + j;
      sf[w * 2048 + l * 32 + (p ^ (l & 31))] = acc[i][j];
    }
  __syncthreads();

  // summer: thread t handles b-row r = t>>3, m-cols (t&7)*8..+7
  {
    const int r = t >> 3, cg = t & 7;
    const int lv = (r >> 2) * 8 + cg;
    float dmin = 3.4e38f;
#pragma unroll
    for (int j = 0; j < 8; ++j) {
      const int p = (r & 3) * 8 + j;
      float s = sf[0 * 2048 + lv * 32 + (p ^ (lv & 31))];
      s += sf[1 * 2048 + lv * 32 + (p ^ (lv & 31))];
      s += sf[2 * 2048 + lv * 32 + (p ^ (lv & 31))];
      s += sf[3 * 2048 + lv * 32 + (p ^ (lv & 31))];
      dmin = fminf(dmin, s);
    }
    dmin = fminf(dmin, __shfl_xor(dmin, 1));
    dmin = fminf(dmin, __shfl_xor(dmin, 2));
    dmin = fminf(dmin, __shfl_xor(dmin, 4));
    if (cg == 0)  // distances >= 0, init +inf -> uint-bit atomicMin valid
      atomicMin((unsigned int*)out + (b0 + r), __float_as_uint(dmin));
  }

  // ---- complete fused copy ----
  float4* mo = (float4*)(out + OFF_MEM);
  float4* dd = (float4*)(out + OFF_MD);
  mo[bid * 512 + t] = cm0;
  mo[bid * 512 + 256 + t] = cm1;
  dd[bid * 256 + t] = cd0;
}

// ---------------------------------------------------------------------------
// K3 (k_scatter): sequential circular-buffer update collapsed to
// ballot/prefix + scatter (count starts at M_LEN so positions wrap from 0).
// ---------------------------------------------------------------------------
__global__ __launch_bounds__(256) void k_scatter(float* __restrict__ out,
                                                 const float* __restrict__ enc,
                                                 const float* __restrict__ x) {
  __shared__ int wcount[4];
  int t = threadIdx.x;
  float l = out[t];  // final loss
  bool cond = isfinite(l) && (l <= BETA);
  unsigned long long m = __ballot(cond);
  int lane = t & 63;
  int wv   = t >> 6;
  int pre_in_wave = __popcll(m & ((1ull << lane) - 1ull));
  if (lane == 0) wcount[wv] = (int)__popcll(m);
  __syncthreads();
  int base = 0;
  for (int w = 0; w < wv; ++w) base += wcount[w];
  if (cond) {
    int pos = base + pre_in_wave;  // (M_LEN + prefix) % M_LEN
    float* mrow = out + OFF_MEM + pos * D_OUT;
    const float* erow = enc + t * D_OUT;
    for (int d = 0; d < D_OUT; ++d) mrow[d] = erow[d];
    float* drow = out + OFF_MD + pos * D_IN;
    const float* xrow = x + t * D_IN;
    for (int d = 0; d < D_IN; ++d) drow[d] = xrow[d];
  }
}

// ---------------------------------------------------------------------------
extern "C" void kernel_launch(void* const* d_in, const int* in_sizes, int n_in,
                              void* d_out, int out_size, void* d_ws, size_t ws_size,
                              hipStream_t stream) {
  const float* x      = (const float*)d_in[0];
  const float* mean   = (const float*)d_in[1];
  const float* stdv   = (const float*)d_in[2];
  const float* W1     = (const float*)d_in[3];
  const float* b1     = (const float*)d_in[4];
  const float* memory = (const float*)d_in[5];
  const float* memdat = (const float*)d_in[6];
  float* out = (float*)d_out;
  float* enc = (float*)d_ws;  // 256*256*4 = 256KB scratch

  k_prep<<<dim3(B_ROWS), dim3(256), 0, stream>>>(x, mean, stdv, W1, b1, enc, out);

  k_dist<<<dim3(M_LEN / TM, B_ROWS / TB), dim3(256), 0, stream>>>(
      enc, memory, (const float4*)memory, (const float4*)memdat, out);

  k_scatter<<<dim3(1), dim3(256), 0, stream>>>(out, enc, x);
}